// Round 8
// baseline (150.326 us; speedup 1.0000x reference)
//
#include <hip/hip_runtime.h>
#include <stdint.h>

#define B_ 64
#define Q_ 900
#define T_ 100
#define C_ 256
#define INF_ 1e9f
#define QT 32       // queries per tile
#define TBLK 12     // cost blocks per batch; tiles bx, bx+12, bx+24
#define NG 8        // target groups per block (tid>>5)
#define TPG 13      // targets per group (last group has 9)
#define SC 101      // s_c stride: bank=(5*qr+t)%32 -> conflict-free transpose
#define KSLOT 15    // ceil(Q_/64) column slots per lane (hungarian)
#define RG 4        // rows per warm-start group
#define NW 16       // waves per hung block (parallel trees) -- r8: 8 -> 16
#define HB 1024     // hung block size (16 waves)

// ---------------------------------------------------------------------------
// Wave64 min-reductions via DPP (verified on HW).
// ---------------------------------------------------------------------------
#define DPP_STEP_F(x, ctrl, rmask)                                             \
    x = fminf(x, __int_as_float(__builtin_amdgcn_update_dpp(                   \
            0x7F800000 /*+inf*/, __float_as_int(x), ctrl, rmask, 0xF, false)))
#define DPP_STEP_I(x, ctrl, rmask)                                             \
    x = min(x, __builtin_amdgcn_update_dpp(                                    \
            0x7FFFFFFF, x, ctrl, rmask, 0xF, false))

__device__ __forceinline__ float wave_min_bcast_f(float x) {
    DPP_STEP_F(x, 0x111, 0xF);   // row_shr:1
    DPP_STEP_F(x, 0x112, 0xF);   // row_shr:2
    DPP_STEP_F(x, 0x114, 0xF);   // row_shr:4
    DPP_STEP_F(x, 0x118, 0xF);   // row_shr:8
    DPP_STEP_F(x, 0x142, 0xA);   // row_bcast:15 -> rows 1,3
    DPP_STEP_F(x, 0x143, 0xC);   // row_bcast:31 -> rows 2,3
    return __int_as_float(__builtin_amdgcn_readlane(__float_as_int(x), 63));
}
__device__ __forceinline__ int wave_min_bcast_i(int x) {
    DPP_STEP_I(x, 0x111, 0xF);
    DPP_STEP_I(x, 0x112, 0xF);
    DPP_STEP_I(x, 0x114, 0xF);
    DPP_STEP_I(x, 0x118, 0xF);
    DPP_STEP_I(x, 0x142, 0xA);
    DPP_STEP_I(x, 0x143, 0xC);
    return __builtin_amdgcn_readlane(x, 63);
}

// ---------------------------------------------------------------------------
// Kernel 1: cost matrix, software-pipelined (unchanged from verified r7).
// ---------------------------------------------------------------------------
__global__ __launch_bounds__(256) void cost_kernel(
    const float* __restrict__ logits,   // [B,Q,C]
    const float* __restrict__ pboxes,   // [B,Q,4] cxcywh
    const int*   __restrict__ tlabels,  // [B,T]
    const float* __restrict__ tboxes,   // [B,T,4] cxcywh
    float* __restrict__ cost_out,       // [B,Q,T]
    float* __restrict__ costT_out)      // [B,T,Q]
{
    const int b   = blockIdx.y;
    const int bx  = blockIdx.x;          // 0..11
    const int tid = threadIdx.x;

    __shared__ float  s_log[QT][C_ + 1]; // 32 x 257 floats = 32.9KB
    __shared__ float  s_c[QT][SC];       // transpose buffer, 12.9KB
    __shared__ float4 s_tb4[T_];
    __shared__ int    s_lab[T_];

    // ---- stage all 100 targets once ----
    if (tid < T_) {
        s_tb4[tid] = *reinterpret_cast<const float4*>(tboxes + ((size_t)b * T_ + tid) * 4);
        s_lab[tid] = tlabels[b * T_ + tid];
    }

    const float* __restrict__ lgb = logits + (size_t)b * Q_ * C_;
    const int nt = (bx < 5) ? 3 : 2;     // tiles bx, bx+12, (bx+24 if bx<5)
    const int qr = tid & 31;
    const int g  = tid >> 5;
    const int tbase = g * TPG;
    const int tcnt  = (T_ - tbase < TPG) ? (T_ - tbase) : TPG;

    // staging lane map: row=idx[8:4], c4=idx[3:0]|idx[10:9]<<4
    //  -> global 4x256B segments/wave; ds_write banks 2-way (free)
    int srow_[8], sc4_[8];
    #pragma unroll
    for (int it = 0; it < 8; ++it) {
        const int idx = it * 256 + tid;
        srow_[it] = (idx >> 4) & 31;
        sc4_[it]  = (idx & 15) | ((idx >> 9) << 4);
    }

    float4 rr[8];
    float4 pbc, pbn;

    // ---- prologue: load tile 0 (regs), write LDS, load pboxes row ----
    {
        const int q0 = bx * QT;
        #pragma unroll
        for (int it = 0; it < 8; ++it) {
            const int q = q0 + srow_[it];
            rr[it] = (q < Q_)
                ? *reinterpret_cast<const float4*>(lgb + (size_t)q * C_ + (sc4_[it] << 2))
                : make_float4(0.f, 0.f, 0.f, 0.f);
        }
        const int q  = q0 + qr;
        const int qc = (q < Q_) ? q : (Q_ - 1);
        pbc = *reinterpret_cast<const float4*>(pboxes + ((size_t)b * Q_ + qc) * 4);
        #pragma unroll
        for (int it = 0; it < 8; ++it) {
            float* d = &s_log[srow_[it]][sc4_[it] << 2];
            d[0] = rr[it].x; d[1] = rr[it].y; d[2] = rr[it].z; d[3] = rr[it].w;
        }
    }
    __syncthreads();

    for (int i = 0; i < nt; ++i) {
        const int q0  = (bx + TBLK * i) * QT;
        const int q   = q0 + qr;
        const bool qok = (q < Q_);
        const bool more = (i + 1 < nt);

        // ---- 1. issue next tile's loads into registers (latency hidden by 2.) ----
        if (more) {
            const int q0n = (bx + TBLK * (i + 1)) * QT;
            #pragma unroll
            for (int it = 0; it < 8; ++it) {
                const int qn = q0n + srow_[it];
                rr[it] = (qn < Q_)
                    ? *reinterpret_cast<const float4*>(lgb + (size_t)qn * C_ + (sc4_[it] << 2))
                    : make_float4(0.f, 0.f, 0.f, 0.f);
            }
            const int qn  = q0n + qr;
            const int qcn = (qn < Q_) ? qn : (Q_ - 1);
            pbn = *reinterpret_cast<const float4*>(pboxes + ((size_t)b * Q_ + qcn) * 4);
        }

        // ---- 2. compute tile i from LDS ----
        const float pcx = pbc.x, pcy = pbc.y, pw = pbc.z, ph = pbc.w;
        const float ax0 = pcx - 0.5f * pw, ay0 = pcy - 0.5f * ph;
        const float ax1 = pcx + 0.5f * pw, ay1 = pcy + 0.5f * ph;
        const float area_a = (ax1 - ax0) * (ay1 - ay0);
        const float* __restrict__ srow = s_log[qr];

        float c[TPG];
        #pragma unroll
        for (int k = 0; k < TPG; ++k) {
            const int t = tbase + ((k < tcnt) ? k : 0);
            const float4 tb = s_tb4[t];
            const float cls = -srow[s_lab[t]];
            const float l1 = fabsf(pcx - tb.x) + fabsf(pcy - tb.y)
                           + fabsf(pw  - tb.z) + fabsf(ph  - tb.w);
            const float bx0 = tb.x - 0.5f * tb.z, by0 = tb.y - 0.5f * tb.w;
            const float bx1 = tb.x + 0.5f * tb.z, by1 = tb.y + 0.5f * tb.w;
            const float area_b = (bx1 - bx0) * (by1 - by0);
            const float ltx = fmaxf(ax0, bx0), lty = fmaxf(ay0, by0);
            const float rbx = fminf(ax1, bx1), rby = fminf(ay1, by1);
            const float wx = fmaxf(rbx - ltx, 0.0f), wy = fmaxf(rby - lty, 0.0f);
            const float inter = wx * wy;
            const float uni = area_a + area_b - inter;
            const float iou = inter / uni;
            const float ex0 = fminf(ax0, bx0), ey0 = fminf(ay0, by0);
            const float ex1 = fmaxf(ax1, bx1), ey1 = fmaxf(ay1, by1);
            const float ew = fmaxf(ex1 - ex0, 0.0f), eh = fmaxf(ey1 - ey0, 0.0f);
            const float enc = ew * eh;
            const float giou = iou - (enc - uni) / enc;
            c[k] = cls + l1 - giou;
        }

        // ---- 3. costT [B,T,Q] stores (q contiguous per half-wave) ----
        if (qok) {
            float* __restrict__ ct = costT_out + (size_t)b * T_ * Q_ + (size_t)tbase * Q_ + q;
            #pragma unroll
            for (int k = 0; k < TPG; ++k)
                if (k < tcnt) ct[(size_t)k * Q_] = c[k];
        }

        // ---- 4. barrier: all waves done reading s_log / s_c free ----
        __syncthreads();

        // ---- 5. transpose into s_c; ds_write prefetched tile into s_log ----
        if (qok) {
            #pragma unroll
            for (int k = 0; k < TPG; ++k)
                if (k < tcnt) s_c[qr][tbase + k] = c[k];
        }
        if (more) {
            #pragma unroll
            for (int it = 0; it < 8; ++it) {
                float* d = &s_log[srow_[it]][sc4_[it] << 2];
                d[0] = rr[it].x; d[1] = rr[it].y; d[2] = rr[it].z; d[3] = rr[it].w;
            }
        }

        // ---- 6. barrier: s_c and next s_log ready ----
        __syncthreads();

        // ---- 7. cost [B,Q,T]: contiguous 32x100 tile writeout ----
        const int nrows = (Q_ - q0 < QT) ? (Q_ - q0) : QT;
        const int ntot  = nrows * T_;
        float* __restrict__ tile = cost_out + ((size_t)b * Q_ + q0) * T_;
        for (int idx = tid; idx < ntot; idx += 256) {
            const int r = idx / T_;
            const int t = idx - r * T_;
            tile[idx] = s_c[r][t];
        }

        pbc = pbn;
    }
}

// ---------------------------------------------------------------------------
// Kernel 2: exact Hungarian. r8: NW=8 -> 16 trees on 1024 threads.
// way_priv narrowed to uint16 (Q_=900 < 65536, sentinel Q_ fits) so
// 16x900 fits LDS (~45KB total); greedy scratch moved to its own int
// array (16-bit atomics unavailable). 4 waves/SIMD latency hiding +
// ~2x fewer super-iterations.
// ---------------------------------------------------------------------------
__global__ __launch_bounds__(HB) void hung_kernel(
    const float* __restrict__ costT,   // [B,T,Q]
    float* __restrict__ out_pred,      // [B,T] as float
    float* __restrict__ out_tgt)       // [B,T] as float
{
    const int b    = blockIdx.x;
    const int tid  = threadIdx.x;
    const int lane = tid & 63;
    const int wave = tid >> 6;
    const float* __restrict__ cb = costT + (size_t)b * T_ * Q_;

    __shared__ float u[128];                       // [100] + pad
    __shared__ float v[Q_];                        // committed column duals
    __shared__ int   p[Q_];                        // committed matching (col -> row)
    __shared__ unsigned short way_priv[NW][Q_];    // per-wave predecessors (u16)
    __shared__ int   s_greedy[Q_];                 // greedy suitor scratch (int atomics)
    __shared__ int   ji[T_];
    __shared__ int   s_pend[T_];
    __shared__ int   col[T_];
    __shared__ int   s_mask[NW][64];               // per-wave tree column masks
    __shared__ int   s_qn, s_acc;

    // ---- init committed state ----
    for (int j = tid; j < Q_; j += HB) {
        p[j] = -1; v[j] = 0.0f; s_greedy[j] = 0x7FFFFFFF;
    }
    if (tid >= 100 && tid < 128) u[tid] = INF_;

    // ---- warm start: u[i] = row min, ji[i] = first argmin (16 waves) ----
    for (int g = wave * RG; g < T_; g += NW * RG) {
        float rv[RG][KSLOT];
        #pragma unroll
        for (int r = 0; r < RG; ++r) {
            const float* __restrict__ row = cb + (size_t)(g + r) * Q_;
            #pragma unroll
            for (int k = 0; k < KSLOT; ++k) {
                int j = k * 64 + lane;
                rv[r][k] = (j < Q_) ? row[j] : INF_;
            }
        }
        #pragma unroll
        for (int r = 0; r < RG; ++r) {
            float m = INF_; int mj = Q_;
            #pragma unroll
            for (int k = 0; k < KSLOT; ++k) {
                int j = k * 64 + lane;
                if (rv[r][k] < m) { m = rv[r][k]; mj = j; }   // strict <: first index
            }
            const float mm = wave_min_bcast_f(m);
            const int   gj = wave_min_bcast_i((m == mm) ? mj : 0x7FFFFFFF);
            if (lane == 0) { u[g + r] = mm; ji[g + r] = gj; }
        }
    }
    __syncthreads();

    // ---- parallel greedy (wave 0): column winner = smallest suitor row ----
    if (wave == 0) {
        int t0 = lane, t1 = lane + 64;
        if (t0 < T_) atomicMin(&s_greedy[ji[t0]], t0);
        if (t1 < T_) atomicMin(&s_greedy[ji[t1]], t1);
        bool lose0 = false, lose1 = false;
        if (t0 < T_) {
            int j = ji[t0];
            if (s_greedy[j] == t0) p[j] = t0; else lose0 = true;
        }
        if (t1 < T_) {
            int j = ji[t1];
            if (s_greedy[j] == t1) p[j] = t1; else lose1 = true;
        }
        unsigned long long m0 = __ballot(lose0);
        unsigned long long m1 = __ballot(lose1);
        const int c0 = __popcll(m0);
        if (lose0) s_pend[__popcll(m0 & ((1ull << lane) - 1ull))] = lane;
        if (lose1) s_pend[c0 + __popcll(m1 & ((1ull << lane) - 1ull))] = lane + 64;
        if (lane == 0) s_qn = c0 + __popcll(m1);
    }

    // ---- super-iterations: up to NW speculative trees, disjoint-commit ----
    for (;;) {
        __syncthreads();                    // commits + queue visible
        const int qn = s_qn;
        if (qn <= 0) break;
        const int nact   = (qn < NW) ? qn : NW;
        const bool active = (wave < nact);
        const int  isrc   = active ? s_pend[wave] : -1;

        // committed snapshots (stable this super-iteration)
        const float u_lo = u[lane];
        const float u_hi = u[64 + lane];
        float vreg[KSLOT];
        #pragma unroll
        for (int k = 0; k < KSLOT; ++k) {
            int j = k * 64 + lane;
            vreg[k] = (j < Q_) ? v[j] : 0.0f;
        }

        unsigned int used = 0;
        float vadd[KSLOT], minv[KSLOT];
        float uisrc_acc = 0.0f;
        int jfin = Q_;

        if (active) {
            unsigned short* __restrict__ wayw = way_priv[wave];
            #pragma unroll
            for (int k = 0; k < KSLOT; ++k) { minv[k] = INF_; vadd[k] = 0.0f; }
            int j0 = Q_;
            uisrc_acc = u[isrc];
            float uicur = uisrc_acc;

            float pre[KSLOT];
            {
                const float* __restrict__ row = cb + (size_t)isrc * Q_;
                #pragma unroll
                for (int k = 0; k < KSLOT; ++k) {
                    int j = k * 64 + lane;
                    pre[k] = (j < Q_) ? row[j] : INF_;
                }
            }

            while (true) {
                float best = INF_; int bj = Q_;
                #pragma unroll
                for (int k = 0; k < KSLOT; ++k) {
                    int j = k * 64 + lane;
                    if (j < Q_ && !((used >> k) & 1u)) {
                        float cur = pre[k] - uicur - vreg[k];
                        if (cur < minv[k]) { minv[k] = cur; wayw[j] = (unsigned short)j0; }
                        float mm = minv[k];
                        if (mm < best) { best = mm; bj = j; }
                    }
                }
                const float delta = wave_min_bcast_f(best);
                const int   j1    = wave_min_bcast_i((best == delta) ? bj : 0x7FFFFFFF);
                const int   inext = p[j1];          // committed (stable)

                // speculative prefetch of next row
                {
                    int ipre = (inext < 0) ? 0 : inext;
                    const float* __restrict__ row = cb + (size_t)ipre * Q_;
                    #pragma unroll
                    for (int k = 0; k < KSLOT; ++k) {
                        int j = k * 64 + lane;
                        pre[k] = (j < Q_) ? row[j] : INF_;
                    }
                }

                // dual updates (j1 counted FREE here, as reference)
                uisrc_acc += delta;
                #pragma unroll
                for (int k = 0; k < KSLOT; ++k) {
                    int j = k * 64 + lane;
                    if (j < Q_) {
                        if ((used >> k) & 1u) vadd[k] += delta;
                        else                  minv[k] -= delta;
                    }
                }

                if (inext < 0) { jfin = j1; break; }

                if (lane == (j1 & 63)) used |= 1u << (j1 >> 6);
                {
                    const int si = __builtin_amdgcn_readfirstlane(inext);
                    const float tsel = (si < 64) ? u_lo : u_hi;
                    uicur = __int_as_float(
                        __builtin_amdgcn_readlane(__float_as_int(tsel), si & 63));
                }
                j0 = j1;
            }
        }

        // publish tree column mask (used cols + final col)
        {
            int msk = active ? (int)used : 0;
            if (active && lane == (jfin & 63)) msk |= 1 << (jfin >> 6);
            s_mask[wave][lane] = msk;
        }
        __syncthreads();

        // acceptance: greedy prefix in pend order, pairwise disjoint (wave 0)
        if (wave == 0) {
            int acc = 1;
            for (int bb = 1; bb < nact; ++bb) {
                int mb = s_mask[bb][lane];
                bool ok = true;
                for (int aa = 0; aa < bb; ++aa) {
                    if ((acc >> aa) & 1) {
                        bool hit = (s_mask[aa][lane] & mb) != 0;
                        if (__ballot(hit) != 0ull) ok = false;
                    }
                }
                if (ok) acc |= 1 << bb;
            }
            if (lane == 0) s_acc = acc;
        }
        __syncthreads();

        // commit accepted trees (disjoint => parallel-safe)
        if (active && ((s_acc >> wave) & 1)) {
            #pragma unroll
            for (int k = 0; k < KSLOT; ++k) {
                int j = k * 64 + lane;
                if (j < Q_ && ((used >> k) & 1u)) {
                    int r = p[j];                  // row matched to j (pre-augment)
                    u[r] = u[r] + vadd[k];
                    v[j] = v[j] - vadd[k];
                }
            }
            if (lane == 0) {
                u[isrc] = uisrc_acc;
                int jj = jfin;
                unsigned short* __restrict__ wayw = way_priv[wave];
                while (true) {
                    int jp = wayw[jj];
                    if (jp == Q_) { p[jj] = isrc; break; }
                    p[jj] = p[jp];
                    jj = jp;
                }
            }
        }
        __syncthreads();

        // rebuild queue (rejected keep order, go to front)
        if (tid == 0) {
            int acc = s_acc;
            int tmp[NW]; int nrej = 0;
            for (int w = 0; w < nact; ++w)
                if (!((acc >> w) & 1)) tmp[nrej++] = s_pend[w];
            for (int i = 0; i < nrej; ++i) s_pend[i] = tmp[i];
            for (int i = nact; i < qn; ++i) s_pend[nrej + i - nact] = s_pend[i];
            s_qn = qn - nact + nrej;
        }
    }

    // ---- outputs: col[t] = assigned query; rank-sort ascending by query ----
    for (int j = tid; j < Q_; j += HB) {
        int r = p[j];
        if (r >= 0) col[r] = j;
    }
    __syncthreads();
    if (tid < T_) {
        int cj = col[tid];
        int rank = 0;
        for (int t2 = 0; t2 < T_; ++t2) rank += (col[t2] < cj) ? 1 : 0;
        out_pred[b * T_ + rank] = (float)cj;
        out_tgt [b * T_ + rank] = (float)tid;
    }
}

extern "C" void kernel_launch(void* const* d_in, const int* in_sizes, int n_in,
                              void* d_out, int out_size, void* d_ws, size_t ws_size,
                              hipStream_t stream) {
    const float* logits  = (const float*)d_in[0];   // [B,Q,C]
    const float* pboxes  = (const float*)d_in[1];   // [B,Q,4]
    const int*   tlabels = (const int*)d_in[2];     // [B,T]
    const float* tboxes  = (const float*)d_in[3];   // [B,T,4]

    float* out      = (float*)d_out;
    float* cost     = out;                                   // [B,Q,T]
    float* out_pred = out + (size_t)B_ * Q_ * T_;            // [B,T]
    float* out_tgt  = out_pred + (size_t)B_ * T_;            // [B,T]

    float* costT = (float*)d_ws;  // [B,T,Q]; ws >= 23 MB proven

    dim3 gridc(TBLK, B_);
    cost_kernel<<<gridc, 256, 0, stream>>>(logits, pboxes, tlabels, tboxes, cost, costT);
    hung_kernel<<<B_, HB, 0, stream>>>(costT, out_pred, out_tgt);
}

// Round 9
// 139.596 us; speedup vs baseline: 1.0769x; 1.0769x over previous
//
#include <hip/hip_runtime.h>
#include <stdint.h>

#define B_ 64
#define Q_ 900
#define T_ 100
#define C_ 256
#define INF_ 1e9f
#define QT 32       // queries per tile
#define TBLK 12     // cost blocks per batch; tiles bx, bx+12, bx+24
#define NG 8        // target groups per block (tid>>5)
#define TPG 13      // targets per group (last group has 9)
#define SC 101      // s_c stride: bank=(5*qr+t)%32 -> conflict-free transpose
#define KSLOT 15    // ceil(Q_/64) column slots per lane (hungarian)
#define RG 4        // rows per warm-start group
#define NW 8        // waves per hung block (parallel trees) -- r9: revert 16 -> 8
#define HB 512      // hung block size (8 waves)

// ---------------------------------------------------------------------------
// Wave64 min-reductions via DPP (verified on HW).
// ---------------------------------------------------------------------------
#define DPP_STEP_F(x, ctrl, rmask)                                             \
    x = fminf(x, __int_as_float(__builtin_amdgcn_update_dpp(                   \
            0x7F800000 /*+inf*/, __float_as_int(x), ctrl, rmask, 0xF, false)))
#define DPP_STEP_I(x, ctrl, rmask)                                             \
    x = min(x, __builtin_amdgcn_update_dpp(                                    \
            0x7FFFFFFF, x, ctrl, rmask, 0xF, false))

__device__ __forceinline__ float wave_min_bcast_f(float x) {
    DPP_STEP_F(x, 0x111, 0xF);   // row_shr:1
    DPP_STEP_F(x, 0x112, 0xF);   // row_shr:2
    DPP_STEP_F(x, 0x114, 0xF);   // row_shr:4
    DPP_STEP_F(x, 0x118, 0xF);   // row_shr:8
    DPP_STEP_F(x, 0x142, 0xA);   // row_bcast:15 -> rows 1,3
    DPP_STEP_F(x, 0x143, 0xC);   // row_bcast:31 -> rows 2,3
    return __int_as_float(__builtin_amdgcn_readlane(__float_as_int(x), 63));
}
__device__ __forceinline__ int wave_min_bcast_i(int x) {
    DPP_STEP_I(x, 0x111, 0xF);
    DPP_STEP_I(x, 0x112, 0xF);
    DPP_STEP_I(x, 0x114, 0xF);
    DPP_STEP_I(x, 0x118, 0xF);
    DPP_STEP_I(x, 0x142, 0xA);
    DPP_STEP_I(x, 0x143, 0xC);
    return __builtin_amdgcn_readlane(x, 63);
}

// ---------------------------------------------------------------------------
// Kernel 1: cost matrix, software-pipelined (verified r7) + float4 writeout.
// ---------------------------------------------------------------------------
__global__ __launch_bounds__(256) void cost_kernel(
    const float* __restrict__ logits,   // [B,Q,C]
    const float* __restrict__ pboxes,   // [B,Q,4] cxcywh
    const int*   __restrict__ tlabels,  // [B,T]
    const float* __restrict__ tboxes,   // [B,T,4] cxcywh
    float* __restrict__ cost_out,       // [B,Q,T]
    float* __restrict__ costT_out)      // [B,T,Q]
{
    const int b   = blockIdx.y;
    const int bx  = blockIdx.x;          // 0..11
    const int tid = threadIdx.x;

    __shared__ float  s_log[QT][C_ + 1]; // 32 x 257 floats = 32.9KB
    __shared__ float  s_c[QT][SC];       // transpose buffer, 12.9KB
    __shared__ float4 s_tb4[T_];
    __shared__ int    s_lab[T_];

    // ---- stage all 100 targets once ----
    if (tid < T_) {
        s_tb4[tid] = *reinterpret_cast<const float4*>(tboxes + ((size_t)b * T_ + tid) * 4);
        s_lab[tid] = tlabels[b * T_ + tid];
    }

    const float* __restrict__ lgb = logits + (size_t)b * Q_ * C_;
    const int nt = (bx < 5) ? 3 : 2;     // tiles bx, bx+12, (bx+24 if bx<5)
    const int qr = tid & 31;
    const int g  = tid >> 5;
    const int tbase = g * TPG;
    const int tcnt  = (T_ - tbase < TPG) ? (T_ - tbase) : TPG;

    // staging lane map: row=idx[8:4], c4=idx[3:0]|idx[10:9]<<4
    //  -> global 4x256B segments/wave; ds_write banks 2-way (free)
    int srow_[8], sc4_[8];
    #pragma unroll
    for (int it = 0; it < 8; ++it) {
        const int idx = it * 256 + tid;
        srow_[it] = (idx >> 4) & 31;
        sc4_[it]  = (idx & 15) | ((idx >> 9) << 4);
    }

    float4 rr[8];
    float4 pbc, pbn;

    // ---- prologue: load tile 0 (regs), write LDS, load pboxes row ----
    {
        const int q0 = bx * QT;
        #pragma unroll
        for (int it = 0; it < 8; ++it) {
            const int q = q0 + srow_[it];
            rr[it] = (q < Q_)
                ? *reinterpret_cast<const float4*>(lgb + (size_t)q * C_ + (sc4_[it] << 2))
                : make_float4(0.f, 0.f, 0.f, 0.f);
        }
        const int q  = q0 + qr;
        const int qc = (q < Q_) ? q : (Q_ - 1);
        pbc = *reinterpret_cast<const float4*>(pboxes + ((size_t)b * Q_ + qc) * 4);
        #pragma unroll
        for (int it = 0; it < 8; ++it) {
            float* d = &s_log[srow_[it]][sc4_[it] << 2];
            d[0] = rr[it].x; d[1] = rr[it].y; d[2] = rr[it].z; d[3] = rr[it].w;
        }
    }
    __syncthreads();

    for (int i = 0; i < nt; ++i) {
        const int q0  = (bx + TBLK * i) * QT;
        const int q   = q0 + qr;
        const bool qok = (q < Q_);
        const bool more = (i + 1 < nt);

        // ---- 1. issue next tile's loads into registers (latency hidden by 2.) ----
        if (more) {
            const int q0n = (bx + TBLK * (i + 1)) * QT;
            #pragma unroll
            for (int it = 0; it < 8; ++it) {
                const int qn = q0n + srow_[it];
                rr[it] = (qn < Q_)
                    ? *reinterpret_cast<const float4*>(lgb + (size_t)qn * C_ + (sc4_[it] << 2))
                    : make_float4(0.f, 0.f, 0.f, 0.f);
            }
            const int qn  = q0n + qr;
            const int qcn = (qn < Q_) ? qn : (Q_ - 1);
            pbn = *reinterpret_cast<const float4*>(pboxes + ((size_t)b * Q_ + qcn) * 4);
        }

        // ---- 2. compute tile i from LDS ----
        const float pcx = pbc.x, pcy = pbc.y, pw = pbc.z, ph = pbc.w;
        const float ax0 = pcx - 0.5f * pw, ay0 = pcy - 0.5f * ph;
        const float ax1 = pcx + 0.5f * pw, ay1 = pcy + 0.5f * ph;
        const float area_a = (ax1 - ax0) * (ay1 - ay0);
        const float* __restrict__ srow = s_log[qr];

        float c[TPG];
        #pragma unroll
        for (int k = 0; k < TPG; ++k) {
            const int t = tbase + ((k < tcnt) ? k : 0);
            const float4 tb = s_tb4[t];
            const float cls = -srow[s_lab[t]];
            const float l1 = fabsf(pcx - tb.x) + fabsf(pcy - tb.y)
                           + fabsf(pw  - tb.z) + fabsf(ph  - tb.w);
            const float bx0 = tb.x - 0.5f * tb.z, by0 = tb.y - 0.5f * tb.w;
            const float bx1 = tb.x + 0.5f * tb.z, by1 = tb.y + 0.5f * tb.w;
            const float area_b = (bx1 - bx0) * (by1 - by0);
            const float ltx = fmaxf(ax0, bx0), lty = fmaxf(ay0, by0);
            const float rbx = fminf(ax1, bx1), rby = fminf(ay1, by1);
            const float wx = fmaxf(rbx - ltx, 0.0f), wy = fmaxf(rby - lty, 0.0f);
            const float inter = wx * wy;
            const float uni = area_a + area_b - inter;
            const float iou = inter / uni;
            const float ex0 = fminf(ax0, bx0), ey0 = fminf(ay0, by0);
            const float ex1 = fmaxf(ax1, bx1), ey1 = fmaxf(ay1, by1);
            const float ew = fmaxf(ex1 - ex0, 0.0f), eh = fmaxf(ey1 - ey0, 0.0f);
            const float enc = ew * eh;
            const float giou = iou - (enc - uni) / enc;
            c[k] = cls + l1 - giou;
        }

        // ---- 3. costT [B,T,Q] stores (q contiguous per half-wave) ----
        if (qok) {
            float* __restrict__ ct = costT_out + (size_t)b * T_ * Q_ + (size_t)tbase * Q_ + q;
            #pragma unroll
            for (int k = 0; k < TPG; ++k)
                if (k < tcnt) ct[(size_t)k * Q_] = c[k];
        }

        // ---- 4. barrier: all waves done reading s_log / s_c free ----
        __syncthreads();

        // ---- 5. transpose into s_c; ds_write prefetched tile into s_log ----
        if (qok) {
            #pragma unroll
            for (int k = 0; k < TPG; ++k)
                if (k < tcnt) s_c[qr][tbase + k] = c[k];
        }
        if (more) {
            #pragma unroll
            for (int it = 0; it < 8; ++it) {
                float* d = &s_log[srow_[it]][sc4_[it] << 2];
                d[0] = rr[it].x; d[1] = rr[it].y; d[2] = rr[it].z; d[3] = rr[it].w;
            }
        }

        // ---- 6. barrier: s_c and next s_log ready ----
        __syncthreads();

        // ---- 7. cost [B,Q,T]: contiguous tile writeout, float4 stores ----
        // tile base offset = 90000*b + 3200*bx floats -> 16B aligned; each
        // 100-float row = exactly 25 float4 slots (100 % 4 == 0).
        const int nrows = (Q_ - q0 < QT) ? (Q_ - q0) : QT;
        const int n4    = (nrows * T_) >> 2;
        float4* __restrict__ tile4 =
            reinterpret_cast<float4*>(cost_out + ((size_t)b * Q_ + q0) * T_);
        for (int s = tid; s < n4; s += 256) {
            const int r  = s / 25;              // 25 float4 per row
            const int t4 = (s - r * 25) << 2;
            tile4[s] = make_float4(s_c[r][t4], s_c[r][t4 + 1],
                                   s_c[r][t4 + 2], s_c[r][t4 + 3]);
        }

        pbc = pbn;
    }
}

// ---------------------------------------------------------------------------
// Kernel 2: exact Hungarian, NW=8 speculatively-parallel SAP trees per batch.
// (verified r7 version; r8's NW=16 was neutral-to-negative -- max-path-length
// and rejection rerun costs eat the TLP gain past 8 trees)
// ---------------------------------------------------------------------------
__global__ __launch_bounds__(HB) void hung_kernel(
    const float* __restrict__ costT,   // [B,T,Q]
    float* __restrict__ out_pred,      // [B,T] as float
    float* __restrict__ out_tgt)       // [B,T] as float
{
    const int b    = blockIdx.x;
    const int tid  = threadIdx.x;
    const int lane = tid & 63;
    const int wave = tid >> 6;
    const float* __restrict__ cb = costT + (size_t)b * T_ * Q_;

    __shared__ float u[128];             // [100] + pad for snapshot reads
    __shared__ float v[Q_];              // committed column duals
    __shared__ int   p[Q_];              // committed matching (col -> row)
    __shared__ int   way_priv[NW][Q_];   // per-wave predecessor arrays
    __shared__ int   ji[T_];
    __shared__ int   s_pend[T_];
    __shared__ int   col[T_];
    __shared__ int   s_mask[NW][64];     // per-wave tree column masks
    __shared__ int   s_qn, s_acc;

    // ---- init committed state ----
    for (int j = tid; j < Q_; j += HB) {
        p[j] = -1; v[j] = 0.0f; way_priv[0][j] = 0x7FFFFFFF;  // [0] = greedy scratch
    }
    if (tid >= 100 && tid < 128) u[tid] = INF_;

    // ---- warm start: u[i] = row min, ji[i] = first argmin (8 waves) ----
    for (int g = wave * RG; g < T_; g += NW * RG) {
        float rv[RG][KSLOT];
        #pragma unroll
        for (int r = 0; r < RG; ++r) {
            const float* __restrict__ row = cb + (size_t)(g + r) * Q_;
            #pragma unroll
            for (int k = 0; k < KSLOT; ++k) {
                int j = k * 64 + lane;
                rv[r][k] = (j < Q_) ? row[j] : INF_;
            }
        }
        #pragma unroll
        for (int r = 0; r < RG; ++r) {
            float m = INF_; int mj = Q_;
            #pragma unroll
            for (int k = 0; k < KSLOT; ++k) {
                int j = k * 64 + lane;
                if (rv[r][k] < m) { m = rv[r][k]; mj = j; }   // strict <: first index
            }
            const float mm = wave_min_bcast_f(m);
            const int   gj = wave_min_bcast_i((m == mm) ? mj : 0x7FFFFFFF);
            if (lane == 0) { u[g + r] = mm; ji[g + r] = gj; }
        }
    }
    __syncthreads();

    // ---- parallel greedy (wave 0): column winner = smallest suitor row ----
    if (wave == 0) {
        int t0 = lane, t1 = lane + 64;
        if (t0 < T_) atomicMin(&way_priv[0][ji[t0]], t0);
        if (t1 < T_) atomicMin(&way_priv[0][ji[t1]], t1);
        bool lose0 = false, lose1 = false;
        if (t0 < T_) {
            int j = ji[t0];
            if (way_priv[0][j] == t0) p[j] = t0; else lose0 = true;
        }
        if (t1 < T_) {
            int j = ji[t1];
            if (way_priv[0][j] == t1) p[j] = t1; else lose1 = true;
        }
        unsigned long long m0 = __ballot(lose0);
        unsigned long long m1 = __ballot(lose1);
        const int c0 = __popcll(m0);
        if (lose0) s_pend[__popcll(m0 & ((1ull << lane) - 1ull))] = lane;
        if (lose1) s_pend[c0 + __popcll(m1 & ((1ull << lane) - 1ull))] = lane + 64;
        if (lane == 0) s_qn = c0 + __popcll(m1);
    }

    // ---- super-iterations: up to NW speculative trees, disjoint-commit ----
    for (;;) {
        __syncthreads();                    // commits + queue visible
        const int qn = s_qn;
        if (qn <= 0) break;
        const int nact   = (qn < NW) ? qn : NW;
        const bool active = (wave < nact);
        const int  isrc   = active ? s_pend[wave] : -1;

        // committed snapshots (stable this super-iteration)
        const float u_lo = u[lane];
        const float u_hi = u[64 + lane];
        float vreg[KSLOT];
        #pragma unroll
        for (int k = 0; k < KSLOT; ++k) {
            int j = k * 64 + lane;
            vreg[k] = (j < Q_) ? v[j] : 0.0f;
        }

        unsigned int used = 0;
        float vadd[KSLOT], minv[KSLOT];
        float uisrc_acc = 0.0f;
        int jfin = Q_;

        if (active) {
            int* __restrict__ wayw = way_priv[wave];
            #pragma unroll
            for (int k = 0; k < KSLOT; ++k) { minv[k] = INF_; vadd[k] = 0.0f; }
            int j0 = Q_;
            uisrc_acc = u[isrc];
            float uicur = uisrc_acc;

            float pre[KSLOT];
            {
                const float* __restrict__ row = cb + (size_t)isrc * Q_;
                #pragma unroll
                for (int k = 0; k < KSLOT; ++k) {
                    int j = k * 64 + lane;
                    pre[k] = (j < Q_) ? row[j] : INF_;
                }
            }

            while (true) {
                float best = INF_; int bj = Q_;
                #pragma unroll
                for (int k = 0; k < KSLOT; ++k) {
                    int j = k * 64 + lane;
                    if (j < Q_ && !((used >> k) & 1u)) {
                        float cur = pre[k] - uicur - vreg[k];
                        if (cur < minv[k]) { minv[k] = cur; wayw[j] = j0; }
                        float mm = minv[k];
                        if (mm < best) { best = mm; bj = j; }
                    }
                }
                const float delta = wave_min_bcast_f(best);
                const int   j1    = wave_min_bcast_i((best == delta) ? bj : 0x7FFFFFFF);
                const int   inext = p[j1];          // committed (stable)

                // speculative prefetch of next row
                {
                    int ipre = (inext < 0) ? 0 : inext;
                    const float* __restrict__ row = cb + (size_t)ipre * Q_;
                    #pragma unroll
                    for (int k = 0; k < KSLOT; ++k) {
                        int j = k * 64 + lane;
                        pre[k] = (j < Q_) ? row[j] : INF_;
                    }
                }

                // dual updates (j1 counted FREE here, as reference)
                uisrc_acc += delta;
                #pragma unroll
                for (int k = 0; k < KSLOT; ++k) {
                    int j = k * 64 + lane;
                    if (j < Q_) {
                        if ((used >> k) & 1u) vadd[k] += delta;
                        else                  minv[k] -= delta;
                    }
                }

                if (inext < 0) { jfin = j1; break; }

                if (lane == (j1 & 63)) used |= 1u << (j1 >> 6);
                {
                    const int si = __builtin_amdgcn_readfirstlane(inext);
                    const float tsel = (si < 64) ? u_lo : u_hi;
                    uicur = __int_as_float(
                        __builtin_amdgcn_readlane(__float_as_int(tsel), si & 63));
                }
                j0 = j1;
            }
        }

        // publish tree column mask (used cols + final col)
        {
            int msk = active ? (int)used : 0;
            if (active && lane == (jfin & 63)) msk |= 1 << (jfin >> 6);
            s_mask[wave][lane] = msk;
        }
        __syncthreads();

        // acceptance: greedy prefix in pend order, pairwise disjoint (wave 0)
        if (wave == 0) {
            int acc = 1;
            for (int bb = 1; bb < nact; ++bb) {
                int mb = s_mask[bb][lane];
                bool ok = true;
                for (int aa = 0; aa < bb; ++aa) {
                    if ((acc >> aa) & 1) {
                        bool hit = (s_mask[aa][lane] & mb) != 0;
                        if (__ballot(hit) != 0ull) ok = false;
                    }
                }
                if (ok) acc |= 1 << bb;
            }
            if (lane == 0) s_acc = acc;
        }
        __syncthreads();

        // commit accepted trees (disjoint => parallel-safe)
        if (active && ((s_acc >> wave) & 1)) {
            #pragma unroll
            for (int k = 0; k < KSLOT; ++k) {
                int j = k * 64 + lane;
                if (j < Q_ && ((used >> k) & 1u)) {
                    int r = p[j];                  // row matched to j (pre-augment)
                    u[r] = u[r] + vadd[k];
                    v[j] = v[j] - vadd[k];
                }
            }
            if (lane == 0) {
                u[isrc] = uisrc_acc;
                int jj = jfin;
                int* __restrict__ wayw = way_priv[wave];
                while (true) {
                    int jp = wayw[jj];
                    if (jp == Q_) { p[jj] = isrc; break; }
                    p[jj] = p[jp];
                    jj = jp;
                }
            }
        }
        __syncthreads();

        // rebuild queue (rejected keep order, go to front)
        if (tid == 0) {
            int acc = s_acc;
            int tmp[NW]; int nrej = 0;
            for (int w = 0; w < nact; ++w)
                if (!((acc >> w) & 1)) tmp[nrej++] = s_pend[w];
            for (int i = 0; i < nrej; ++i) s_pend[i] = tmp[i];
            for (int i = nact; i < qn; ++i) s_pend[nrej + i - nact] = s_pend[i];
            s_qn = qn - nact + nrej;
        }
    }

    // ---- outputs: col[t] = assigned query; rank-sort ascending by query ----
    for (int j = tid; j < Q_; j += HB) {
        int r = p[j];
        if (r >= 0) col[r] = j;
    }
    __syncthreads();
    if (tid < T_) {
        int cj = col[tid];
        int rank = 0;
        for (int t2 = 0; t2 < T_; ++t2) rank += (col[t2] < cj) ? 1 : 0;
        out_pred[b * T_ + rank] = (float)cj;
        out_tgt [b * T_ + rank] = (float)tid;
    }
}

extern "C" void kernel_launch(void* const* d_in, const int* in_sizes, int n_in,
                              void* d_out, int out_size, void* d_ws, size_t ws_size,
                              hipStream_t stream) {
    const float* logits  = (const float*)d_in[0];   // [B,Q,C]
    const float* pboxes  = (const float*)d_in[1];   // [B,Q,4]
    const int*   tlabels = (const int*)d_in[2];     // [B,T]
    const float* tboxes  = (const float*)d_in[3];   // [B,T,4]

    float* out      = (float*)d_out;
    float* cost     = out;                                   // [B,Q,T]
    float* out_pred = out + (size_t)B_ * Q_ * T_;            // [B,T]
    float* out_tgt  = out_pred + (size_t)B_ * T_;            // [B,T]

    float* costT = (float*)d_ws;  // [B,T,Q]; ws >= 23 MB proven

    dim3 gridc(TBLK, B_);
    cost_kernel<<<gridc, 256, 0, stream>>>(logits, pboxes, tlabels, tboxes, cost, costT);
    hung_kernel<<<B_, HB, 0, stream>>>(costT, out_pred, out_tgt);
}

// Round 10
// 139.458 us; speedup vs baseline: 1.0779x; 1.0010x over previous
//
#include <hip/hip_runtime.h>
#include <stdint.h>

#define B_ 64
#define Q_ 900
#define T_ 100
#define C_ 256
#define INF_ 1e9f
#define QT 32       // queries per tile
#define TBLK 12     // cost blocks per batch; tiles bx, bx+12, bx+24
#define NG 8        // target groups per block (tid>>5)
#define TPG 13      // targets per group (last group has 9)
#define SC 101      // s_c stride: bank=(5*qr+t)%32 -> conflict-free transpose
#define KSLOT 15    // ceil(Q_/64) column slots per lane (hungarian)
#define RG 4        // rows per warm-start group
#define NW 8        // waves per hung block (parallel trees)
#define HB 512      // hung block size (8 waves)

// ---------------------------------------------------------------------------
// Wave64 float min-reduction via DPP (verified on HW). Index selection now
// uses ballot+ffs+readlane (r10): one 6-step DPP chain instead of two.
// ---------------------------------------------------------------------------
#define DPP_STEP_F(x, ctrl, rmask)                                             \
    x = fminf(x, __int_as_float(__builtin_amdgcn_update_dpp(                   \
            0x7F800000 /*+inf*/, __float_as_int(x), ctrl, rmask, 0xF, false)))

__device__ __forceinline__ float wave_min_bcast_f(float x) {
    DPP_STEP_F(x, 0x111, 0xF);   // row_shr:1
    DPP_STEP_F(x, 0x112, 0xF);   // row_shr:2
    DPP_STEP_F(x, 0x114, 0xF);   // row_shr:4
    DPP_STEP_F(x, 0x118, 0xF);   // row_shr:8
    DPP_STEP_F(x, 0x142, 0xA);   // row_bcast:15 -> rows 1,3
    DPP_STEP_F(x, 0x143, 0xC);   // row_bcast:31 -> rows 2,3
    return __int_as_float(__builtin_amdgcn_readlane(__float_as_int(x), 63));
}

// argmin companion: first lane whose local best equals the wave min; return
// that lane's local argmin index. Any argmin is valid for JV (optimum a.s.
// unique), so the lane-order tie-break is safe.
__device__ __forceinline__ int wave_argmin_pick(float best, float delta, int bj) {
    unsigned long long m = __ballot(best == delta);
    const int wl = (int)__ffsll((long long)m) - 1;
    return __builtin_amdgcn_readlane(bj, wl);
}

// ---------------------------------------------------------------------------
// Kernel 1: cost matrix, software-pipelined (verified r7) + float4 writeout
// (verified r9). Unchanged.
// ---------------------------------------------------------------------------
__global__ __launch_bounds__(256) void cost_kernel(
    const float* __restrict__ logits,   // [B,Q,C]
    const float* __restrict__ pboxes,   // [B,Q,4] cxcywh
    const int*   __restrict__ tlabels,  // [B,T]
    const float* __restrict__ tboxes,   // [B,T,4] cxcywh
    float* __restrict__ cost_out,       // [B,Q,T]
    float* __restrict__ costT_out)      // [B,T,Q]
{
    const int b   = blockIdx.y;
    const int bx  = blockIdx.x;          // 0..11
    const int tid = threadIdx.x;

    __shared__ float  s_log[QT][C_ + 1]; // 32 x 257 floats = 32.9KB
    __shared__ float  s_c[QT][SC];       // transpose buffer, 12.9KB
    __shared__ float4 s_tb4[T_];
    __shared__ int    s_lab[T_];

    // ---- stage all 100 targets once ----
    if (tid < T_) {
        s_tb4[tid] = *reinterpret_cast<const float4*>(tboxes + ((size_t)b * T_ + tid) * 4);
        s_lab[tid] = tlabels[b * T_ + tid];
    }

    const float* __restrict__ lgb = logits + (size_t)b * Q_ * C_;
    const int nt = (bx < 5) ? 3 : 2;     // tiles bx, bx+12, (bx+24 if bx<5)
    const int qr = tid & 31;
    const int g  = tid >> 5;
    const int tbase = g * TPG;
    const int tcnt  = (T_ - tbase < TPG) ? (T_ - tbase) : TPG;

    // staging lane map: row=idx[8:4], c4=idx[3:0]|idx[10:9]<<4
    //  -> global 4x256B segments/wave; ds_write banks 2-way (free)
    int srow_[8], sc4_[8];
    #pragma unroll
    for (int it = 0; it < 8; ++it) {
        const int idx = it * 256 + tid;
        srow_[it] = (idx >> 4) & 31;
        sc4_[it]  = (idx & 15) | ((idx >> 9) << 4);
    }

    float4 rr[8];
    float4 pbc, pbn;

    // ---- prologue: load tile 0 (regs), write LDS, load pboxes row ----
    {
        const int q0 = bx * QT;
        #pragma unroll
        for (int it = 0; it < 8; ++it) {
            const int q = q0 + srow_[it];
            rr[it] = (q < Q_)
                ? *reinterpret_cast<const float4*>(lgb + (size_t)q * C_ + (sc4_[it] << 2))
                : make_float4(0.f, 0.f, 0.f, 0.f);
        }
        const int q  = q0 + qr;
        const int qc = (q < Q_) ? q : (Q_ - 1);
        pbc = *reinterpret_cast<const float4*>(pboxes + ((size_t)b * Q_ + qc) * 4);
        #pragma unroll
        for (int it = 0; it < 8; ++it) {
            float* d = &s_log[srow_[it]][sc4_[it] << 2];
            d[0] = rr[it].x; d[1] = rr[it].y; d[2] = rr[it].z; d[3] = rr[it].w;
        }
    }
    __syncthreads();

    for (int i = 0; i < nt; ++i) {
        const int q0  = (bx + TBLK * i) * QT;
        const int q   = q0 + qr;
        const bool qok = (q < Q_);
        const bool more = (i + 1 < nt);

        // ---- 1. issue next tile's loads into registers (latency hidden by 2.) ----
        if (more) {
            const int q0n = (bx + TBLK * (i + 1)) * QT;
            #pragma unroll
            for (int it = 0; it < 8; ++it) {
                const int qn = q0n + srow_[it];
                rr[it] = (qn < Q_)
                    ? *reinterpret_cast<const float4*>(lgb + (size_t)qn * C_ + (sc4_[it] << 2))
                    : make_float4(0.f, 0.f, 0.f, 0.f);
            }
            const int qn  = q0n + qr;
            const int qcn = (qn < Q_) ? qn : (Q_ - 1);
            pbn = *reinterpret_cast<const float4*>(pboxes + ((size_t)b * Q_ + qcn) * 4);
        }

        // ---- 2. compute tile i from LDS ----
        const float pcx = pbc.x, pcy = pbc.y, pw = pbc.z, ph = pbc.w;
        const float ax0 = pcx - 0.5f * pw, ay0 = pcy - 0.5f * ph;
        const float ax1 = pcx + 0.5f * pw, ay1 = pcy + 0.5f * ph;
        const float area_a = (ax1 - ax0) * (ay1 - ay0);
        const float* __restrict__ srow = s_log[qr];

        float c[TPG];
        #pragma unroll
        for (int k = 0; k < TPG; ++k) {
            const int t = tbase + ((k < tcnt) ? k : 0);
            const float4 tb = s_tb4[t];
            const float cls = -srow[s_lab[t]];
            const float l1 = fabsf(pcx - tb.x) + fabsf(pcy - tb.y)
                           + fabsf(pw  - tb.z) + fabsf(ph  - tb.w);
            const float bx0 = tb.x - 0.5f * tb.z, by0 = tb.y - 0.5f * tb.w;
            const float bx1 = tb.x + 0.5f * tb.z, by1 = tb.y + 0.5f * tb.w;
            const float area_b = (bx1 - bx0) * (by1 - by0);
            const float ltx = fmaxf(ax0, bx0), lty = fmaxf(ay0, by0);
            const float rbx = fminf(ax1, bx1), rby = fminf(ay1, by1);
            const float wx = fmaxf(rbx - ltx, 0.0f), wy = fmaxf(rby - lty, 0.0f);
            const float inter = wx * wy;
            const float uni = area_a + area_b - inter;
            const float iou = inter / uni;
            const float ex0 = fminf(ax0, bx0), ey0 = fminf(ay0, by0);
            const float ex1 = fmaxf(ax1, bx1), ey1 = fmaxf(ay1, by1);
            const float ew = fmaxf(ex1 - ex0, 0.0f), eh = fmaxf(ey1 - ey0, 0.0f);
            const float enc = ew * eh;
            const float giou = iou - (enc - uni) / enc;
            c[k] = cls + l1 - giou;
        }

        // ---- 3. costT [B,T,Q] stores (q contiguous per half-wave) ----
        if (qok) {
            float* __restrict__ ct = costT_out + (size_t)b * T_ * Q_ + (size_t)tbase * Q_ + q;
            #pragma unroll
            for (int k = 0; k < TPG; ++k)
                if (k < tcnt) ct[(size_t)k * Q_] = c[k];
        }

        // ---- 4. barrier: all waves done reading s_log / s_c free ----
        __syncthreads();

        // ---- 5. transpose into s_c; ds_write prefetched tile into s_log ----
        if (qok) {
            #pragma unroll
            for (int k = 0; k < TPG; ++k)
                if (k < tcnt) s_c[qr][tbase + k] = c[k];
        }
        if (more) {
            #pragma unroll
            for (int it = 0; it < 8; ++it) {
                float* d = &s_log[srow_[it]][sc4_[it] << 2];
                d[0] = rr[it].x; d[1] = rr[it].y; d[2] = rr[it].z; d[3] = rr[it].w;
            }
        }

        // ---- 6. barrier: s_c and next s_log ready ----
        __syncthreads();

        // ---- 7. cost [B,Q,T]: contiguous tile writeout, float4 stores ----
        const int nrows = (Q_ - q0 < QT) ? (Q_ - q0) : QT;
        const int n4    = (nrows * T_) >> 2;
        float4* __restrict__ tile4 =
            reinterpret_cast<float4*>(cost_out + ((size_t)b * Q_ + q0) * T_);
        for (int s = tid; s < n4; s += 256) {
            const int r  = s / 25;              // 25 float4 per row
            const int t4 = (s - r * 25) << 2;
            tile4[s] = make_float4(s_c[r][t4], s_c[r][t4 + 1],
                                   s_c[r][t4 + 2], s_c[r][t4 + 3]);
        }

        pbc = pbn;
    }
}

// ---------------------------------------------------------------------------
// Kernel 2: exact Hungarian, NW=8 speculative SAP trees (verified r7), with
// r10 ballot-argmin: the serial per-iteration chain drops one 6-step DPP
// reduction (float min kept; index pick = ballot+ffs+readlane).
// ---------------------------------------------------------------------------
__global__ __launch_bounds__(HB) void hung_kernel(
    const float* __restrict__ costT,   // [B,T,Q]
    float* __restrict__ out_pred,      // [B,T] as float
    float* __restrict__ out_tgt)       // [B,T] as float
{
    const int b    = blockIdx.x;
    const int tid  = threadIdx.x;
    const int lane = tid & 63;
    const int wave = tid >> 6;
    const float* __restrict__ cb = costT + (size_t)b * T_ * Q_;

    __shared__ float u[128];             // [100] + pad for snapshot reads
    __shared__ float v[Q_];              // committed column duals
    __shared__ int   p[Q_];              // committed matching (col -> row)
    __shared__ int   way_priv[NW][Q_];   // per-wave predecessor arrays
    __shared__ int   ji[T_];
    __shared__ int   s_pend[T_];
    __shared__ int   col[T_];
    __shared__ int   s_mask[NW][64];     // per-wave tree column masks
    __shared__ int   s_qn, s_acc;

    // ---- init committed state ----
    for (int j = tid; j < Q_; j += HB) {
        p[j] = -1; v[j] = 0.0f; way_priv[0][j] = 0x7FFFFFFF;  // [0] = greedy scratch
    }
    if (tid >= 100 && tid < 128) u[tid] = INF_;

    // ---- warm start: u[i] = row min, ji[i] = argmin (8 waves) ----
    for (int g = wave * RG; g < T_; g += NW * RG) {
        float rv[RG][KSLOT];
        #pragma unroll
        for (int r = 0; r < RG; ++r) {
            const float* __restrict__ row = cb + (size_t)(g + r) * Q_;
            #pragma unroll
            for (int k = 0; k < KSLOT; ++k) {
                int j = k * 64 + lane;
                rv[r][k] = (j < Q_) ? row[j] : INF_;
            }
        }
        #pragma unroll
        for (int r = 0; r < RG; ++r) {
            float m = INF_; int mj = Q_;
            #pragma unroll
            for (int k = 0; k < KSLOT; ++k) {
                int j = k * 64 + lane;
                if (rv[r][k] < m) { m = rv[r][k]; mj = j; }   // strict <: lane-local first
            }
            const float mm = wave_min_bcast_f(m);
            const int   gj = wave_argmin_pick(m, mm, mj);
            if (lane == 0) { u[g + r] = mm; ji[g + r] = gj; }
        }
    }
    __syncthreads();

    // ---- parallel greedy (wave 0): column winner = smallest suitor row ----
    if (wave == 0) {
        int t0 = lane, t1 = lane + 64;
        if (t0 < T_) atomicMin(&way_priv[0][ji[t0]], t0);
        if (t1 < T_) atomicMin(&way_priv[0][ji[t1]], t1);
        bool lose0 = false, lose1 = false;
        if (t0 < T_) {
            int j = ji[t0];
            if (way_priv[0][j] == t0) p[j] = t0; else lose0 = true;
        }
        if (t1 < T_) {
            int j = ji[t1];
            if (way_priv[0][j] == t1) p[j] = t1; else lose1 = true;
        }
        unsigned long long m0 = __ballot(lose0);
        unsigned long long m1 = __ballot(lose1);
        const int c0 = __popcll(m0);
        if (lose0) s_pend[__popcll(m0 & ((1ull << lane) - 1ull))] = lane;
        if (lose1) s_pend[c0 + __popcll(m1 & ((1ull << lane) - 1ull))] = lane + 64;
        if (lane == 0) s_qn = c0 + __popcll(m1);
    }

    // ---- super-iterations: up to NW speculative trees, disjoint-commit ----
    for (;;) {
        __syncthreads();                    // commits + queue visible
        const int qn = s_qn;
        if (qn <= 0) break;
        const int nact   = (qn < NW) ? qn : NW;
        const bool active = (wave < nact);
        const int  isrc   = active ? s_pend[wave] : -1;

        // committed snapshots (stable this super-iteration)
        const float u_lo = u[lane];
        const float u_hi = u[64 + lane];
        float vreg[KSLOT];
        #pragma unroll
        for (int k = 0; k < KSLOT; ++k) {
            int j = k * 64 + lane;
            vreg[k] = (j < Q_) ? v[j] : 0.0f;
        }

        unsigned int used = 0;
        float vadd[KSLOT], minv[KSLOT];
        float uisrc_acc = 0.0f;
        int jfin = Q_;

        if (active) {
            int* __restrict__ wayw = way_priv[wave];
            #pragma unroll
            for (int k = 0; k < KSLOT; ++k) { minv[k] = INF_; vadd[k] = 0.0f; }
            int j0 = Q_;
            uisrc_acc = u[isrc];
            float uicur = uisrc_acc;

            float pre[KSLOT];
            {
                const float* __restrict__ row = cb + (size_t)isrc * Q_;
                #pragma unroll
                for (int k = 0; k < KSLOT; ++k) {
                    int j = k * 64 + lane;
                    pre[k] = (j < Q_) ? row[j] : INF_;
                }
            }

            while (true) {
                float best = INF_; int bj = Q_;
                #pragma unroll
                for (int k = 0; k < KSLOT; ++k) {
                    int j = k * 64 + lane;
                    if (j < Q_ && !((used >> k) & 1u)) {
                        float cur = pre[k] - uicur - vreg[k];
                        if (cur < minv[k]) { minv[k] = cur; wayw[j] = j0; }
                        float mm = minv[k];
                        if (mm < best) { best = mm; bj = j; }
                    }
                }
                const float delta = wave_min_bcast_f(best);
                const int   j1    = wave_argmin_pick(best, delta, bj);
                const int   inext = p[j1];          // committed (stable)

                // speculative prefetch of next row
                {
                    int ipre = (inext < 0) ? 0 : inext;
                    const float* __restrict__ row = cb + (size_t)ipre * Q_;
                    #pragma unroll
                    for (int k = 0; k < KSLOT; ++k) {
                        int j = k * 64 + lane;
                        pre[k] = (j < Q_) ? row[j] : INF_;
                    }
                }

                // dual updates (j1 counted FREE here, as reference)
                uisrc_acc += delta;
                #pragma unroll
                for (int k = 0; k < KSLOT; ++k) {
                    int j = k * 64 + lane;
                    if (j < Q_) {
                        if ((used >> k) & 1u) vadd[k] += delta;
                        else                  minv[k] -= delta;
                    }
                }

                if (inext < 0) { jfin = j1; break; }

                if (lane == (j1 & 63)) used |= 1u << (j1 >> 6);
                {
                    const int si = __builtin_amdgcn_readfirstlane(inext);
                    const float tsel = (si < 64) ? u_lo : u_hi;
                    uicur = __int_as_float(
                        __builtin_amdgcn_readlane(__float_as_int(tsel), si & 63));
                }
                j0 = j1;
            }
        }

        // publish tree column mask (used cols + final col)
        {
            int msk = active ? (int)used : 0;
            if (active && lane == (jfin & 63)) msk |= 1 << (jfin >> 6);
            s_mask[wave][lane] = msk;
        }
        __syncthreads();

        // acceptance: greedy prefix in pend order, pairwise disjoint (wave 0)
        if (wave == 0) {
            int acc = 1;
            for (int bb = 1; bb < nact; ++bb) {
                int mb = s_mask[bb][lane];
                bool ok = true;
                for (int aa = 0; aa < bb; ++aa) {
                    if ((acc >> aa) & 1) {
                        bool hit = (s_mask[aa][lane] & mb) != 0;
                        if (__ballot(hit) != 0ull) ok = false;
                    }
                }
                if (ok) acc |= 1 << bb;
            }
            if (lane == 0) s_acc = acc;
        }
        __syncthreads();

        // commit accepted trees (disjoint => parallel-safe)
        if (active && ((s_acc >> wave) & 1)) {
            #pragma unroll
            for (int k = 0; k < KSLOT; ++k) {
                int j = k * 64 + lane;
                if (j < Q_ && ((used >> k) & 1u)) {
                    int r = p[j];                  // row matched to j (pre-augment)
                    u[r] = u[r] + vadd[k];
                    v[j] = v[j] - vadd[k];
                }
            }
            if (lane == 0) {
                u[isrc] = uisrc_acc;
                int jj = jfin;
                int* __restrict__ wayw = way_priv[wave];
                while (true) {
                    int jp = wayw[jj];
                    if (jp == Q_) { p[jj] = isrc; break; }
                    p[jj] = p[jp];
                    jj = jp;
                }
            }
        }
        __syncthreads();

        // rebuild queue (rejected keep order, go to front)
        if (tid == 0) {
            int acc = s_acc;
            int tmp[NW]; int nrej = 0;
            for (int w = 0; w < nact; ++w)
                if (!((acc >> w) & 1)) tmp[nrej++] = s_pend[w];
            for (int i = 0; i < nrej; ++i) s_pend[i] = tmp[i];
            for (int i = nact; i < qn; ++i) s_pend[nrej + i - nact] = s_pend[i];
            s_qn = qn - nact + nrej;
        }
    }

    // ---- outputs: col[t] = assigned query; rank-sort ascending by query ----
    for (int j = tid; j < Q_; j += HB) {
        int r = p[j];
        if (r >= 0) col[r] = j;
    }
    __syncthreads();
    if (tid < T_) {
        int cj = col[tid];
        int rank = 0;
        for (int t2 = 0; t2 < T_; ++t2) rank += (col[t2] < cj) ? 1 : 0;
        out_pred[b * T_ + rank] = (float)cj;
        out_tgt [b * T_ + rank] = (float)tid;
    }
}

extern "C" void kernel_launch(void* const* d_in, const int* in_sizes, int n_in,
                              void* d_out, int out_size, void* d_ws, size_t ws_size,
                              hipStream_t stream) {
    const float* logits  = (const float*)d_in[0];   // [B,Q,C]
    const float* pboxes  = (const float*)d_in[1];   // [B,Q,4]
    const int*   tlabels = (const int*)d_in[2];     // [B,T]
    const float* tboxes  = (const float*)d_in[3];   // [B,T,4]

    float* out      = (float*)d_out;
    float* cost     = out;                                   // [B,Q,T]
    float* out_pred = out + (size_t)B_ * Q_ * T_;            // [B,T]
    float* out_tgt  = out_pred + (size_t)B_ * T_;            // [B,T]

    float* costT = (float*)d_ws;  // [B,T,Q]; ws >= 23 MB proven

    dim3 gridc(TBLK, B_);
    cost_kernel<<<gridc, 256, 0, stream>>>(logits, pboxes, tlabels, tboxes, cost, costT);
    hung_kernel<<<B_, HB, 0, stream>>>(costT, out_pred, out_tgt);
}